// Round 19
// baseline (230.305 us; speedup 1.0000x reference)
//
#include <hip/hip_runtime.h>

#define NN 100000
#define NE 600000
#define NP 100096   // 391*256, padded node count
#define NB 391
#define NBE 9375    // NE/64 edge blocks

typedef float v4    __attribute__((ext_vector_type(4)));
typedef float f32x4 __attribute__((ext_vector_type(4)));
typedef short s16x4 __attribute__((ext_vector_type(4)));
typedef short s16x8 __attribute__((ext_vector_type(8)));

__device__ __forceinline__ short f2bf(float f) {
    unsigned u = __float_as_uint(f);
    u = (u + 0x7fffu + ((u >> 16) & 1u)) >> 16;
    return (short)u;
}
__device__ __forceinline__ float bf2f(unsigned short v) {
    return __uint_as_float(((unsigned)v) << 16);
}

// ---------------------------------------------------------------------------
// hist + weight-prep + xu-pack fused. xu[n][8] = [x0,x1,u0,u1,0...] bf16 —
// consumed by node L1 ks==4 fragment (direct global read).
// ---------------------------------------------------------------------------
__global__ __launch_bounds__(256) void hist_prep_kernel(
    const int* __restrict__ ei, int* __restrict__ deg,
    const float* __restrict__ x, const float* __restrict__ u,
    const int* __restrict__ batch,
    const float* __restrict__ W2a, const float* __restrict__ W2b,
    const float* __restrict__ W1a, const float* __restrict__ W1b,
    short* __restrict__ W2aF, short* __restrict__ W2bF,
    short* __restrict__ W1aT, short* __restrict__ W1bT,
    short* __restrict__ xu)
{
    int idx = blockIdx.x * 256 + threadIdx.x;
    if (idx < NE) atomicAdd(&deg[ei[idx]], 1);

    if (idx < NN) {
        s16x8 p = {0, 0, 0, 0, 0, 0, 0, 0};
        p[0] = f2bf(x[2 * idx]); p[1] = f2bf(x[2 * idx + 1]);
        int b = batch[idx];
        p[2] = f2bf(u[2 * b]); p[3] = f2bf(u[2 * b + 1]);
        *(s16x8*)&xu[(size_t)idx * 8] = p;
    }

    if (idx < 16 * 5 * 512) {                     // W2aF: 40960
        int j = idx & 7;
        int lane = (idx >> 3) & 63;
        int t2 = idx >> 9;
        int ks = t2 % 5, nb = t2 / 5;
        int n = nb * 16 + (lane & 15);
        int k = ks * 32 + (lane >> 4) * 8 + j;    // < 160
        float v = 0.f;
        if (k < 128)       v = W2a[(2 + k) * 256 + n];
        else if (k == 128) v = W2a[0 * 256 + n];
        else if (k == 129) v = W2a[1 * 256 + n];
        else if (k == 130) v = W2a[130 * 256 + n];
        else if (k == 131) v = W2a[131 * 256 + n];
        W2aF[idx] = f2bf(v);
    }
    if (idx < 32 * 8 * 512) {                     // W2bF: 131072
        int j = idx & 7;
        int lane = (idx >> 3) & 63;
        int t2 = idx >> 9;
        int ks = t2 & 7, nb = t2 >> 3;
        int n = nb * 16 + (lane & 15);
        int k = ks * 32 + (lane >> 4) * 8 + j;    // < 256
        W2bF[idx] = f2bf(W2b[k * 512 + n]);
    }
    if (idx < 64 * 32) {
        int n = idx >> 5, k = idx & 31;
        W1aT[idx] = (k < 4) ? f2bf(W1a[k * 64 + n]) : (short)0;
    }
    if (idx < 128 * 64) {
        int n = idx >> 6, k = idx & 63;
        W1bT[idx] = f2bf(W1b[k * 128 + n]);
    }
}

__global__ __launch_bounds__(256) void scan1_kernel(const int* __restrict__ deg,
                                                    int* __restrict__ partial,
                                                    int* __restrict__ bsum) {
    __shared__ int tmp[256];
    int t = threadIdx.x;
    int i = blockIdx.x * 256 + t;
    int v = deg[i];
    tmp[t] = v;
    __syncthreads();
    for (int off = 1; off < 256; off <<= 1) {
        int add = (t >= off) ? tmp[t - off] : 0;
        __syncthreads();
        tmp[t] += add;
        __syncthreads();
    }
    partial[i] = tmp[t] - v;
    if (t == 255) bsum[blockIdx.x] = tmp[255];
}

__global__ __launch_bounds__(512) void scan2_kernel(const int* __restrict__ bsum,
                                                    int* __restrict__ boff) {
    __shared__ int tmp[512];
    int t = threadIdx.x;
    int v = (t < NB) ? bsum[t] : 0;
    tmp[t] = v;
    __syncthreads();
    for (int off = 1; off < 512; off <<= 1) {
        int add = (t >= off) ? tmp[t - off] : 0;
        __syncthreads();
        tmp[t] += add;
        __syncthreads();
    }
    boff[t] = tmp[t] - v;
}

__global__ __launch_bounds__(256) void fill_kernel(const int* __restrict__ ei,
                                                   const float* __restrict__ x,
                                                   const float* __restrict__ ea,
                                                   const int* __restrict__ partial,
                                                   const int* __restrict__ boff,
                                                   int* __restrict__ cnt2,
                                                   int* __restrict__ rowp,
                                                   short* __restrict__ in_csr) {
    int e = blockIdx.x * 256 + threadIdx.x;
    if (e < NE) {
        int r = ei[e];
        int c = ei[NE + e];
        int p = partial[r] + boff[r >> 8] + atomicAdd(&cnt2[r], 1);
        rowp[p] = r;
        s16x8 v = {0, 0, 0, 0, 0, 0, 0, 0};
        v[0] = f2bf(x[2 * c]);  v[1] = f2bf(x[2 * c + 1]);
        v[2] = f2bf(ea[2 * e]); v[3] = f2bf(ea[2 * e + 1]);
        *(s16x8*)&in_csr[(size_t)p * 8] = v;
    }
}

// ---------------------------------------------------------------------------
// Edge fused v4 (unchanged from R18): direct-global L1 input, LDS pool union,
// 3 barriers, interior -> aggb, boundary partials -> pend/pstart.
// ---------------------------------------------------------------------------
__global__ __launch_bounds__(256, 8) void edge_fused_kernel(
    const short* __restrict__ in_csr, const int* __restrict__ rowp,
    const short* __restrict__ W1aT, const short* __restrict__ W1bT,
    const float* __restrict__ b1a, const float* __restrict__ b1b,
    const int* __restrict__ partial, const int* __restrict__ boff,
    const int* __restrict__ deg,
    short* __restrict__ aggb, float* __restrict__ pstart,
    float* __restrict__ pend)
{
    __shared__ short pool[64 * 136];  // union: t1[64*72] then hbf[64*136]
    __shared__ int   rows[64];
    __shared__ float midlo[128], midhi[128];
    short* t1  = pool;
    short* hbf = pool;
    const int tid = threadIdx.x;
    const int p0 = blockIdx.x * 64;

    if (tid < 64) rows[tid] = rowp[p0 + tid];

    const int lane = tid & 63, nw = tid >> 6;
    const int l15 = lane & 15, lk = lane >> 4;

    f32x4 a1[4];
#pragma unroll
    for (int bf = 0; bf < 4; ++bf) a1[bf] = (f32x4){0.f, 0.f, 0.f, 0.f};
    {
        s16x8 wA = *(const s16x8*)&W1aT[(nw * 16 + l15) * 32 + lk * 8];
        s16x8 zz = {0, 0, 0, 0, 0, 0, 0, 0};
#pragma unroll
        for (int bf = 0; bf < 4; ++bf) {
            s16x8 bI = zz;
            if (lk == 0)
                bI = *(const s16x8*)&in_csr[(size_t)(p0 + bf * 16 + l15) * 8];
            a1[bf] = __builtin_amdgcn_mfma_f32_16x16x32_bf16(wA, bI, a1[bf], 0, 0, 0);
        }
    }
    {
        f32x4 bias = *(const f32x4*)&b1a[nw * 16 + lk * 4];
#pragma unroll
        for (int bf = 0; bf < 4; ++bf) {
            s16x4 pk;
#pragma unroll
            for (int j = 0; j < 4; ++j)
                pk[j] = f2bf(fmaxf(a1[bf][j] + bias[j], 0.f));
            *(s16x4*)&t1[(bf * 16 + l15) * 72 + nw * 16 + lk * 4] = pk;
        }
    }
    __syncthreads();

    f32x4 a2[2][4];
#pragma unroll
    for (int af = 0; af < 2; ++af)
#pragma unroll
        for (int bf = 0; bf < 4; ++bf) a2[af][bf] = (f32x4){0.f, 0.f, 0.f, 0.f};

#pragma unroll
    for (int ks = 0; ks < 2; ++ks) {
        s16x8 w[2], b[4];
#pragma unroll
        for (int af = 0; af < 2; ++af)
            w[af] = *(const s16x8*)&W1bT[((nw * 2 + af) * 16 + l15) * 64 + ks * 32 + lk * 8];
#pragma unroll
        for (int bf = 0; bf < 4; ++bf)
            b[bf] = *(const s16x8*)&t1[(bf * 16 + l15) * 72 + ks * 32 + lk * 8];
#pragma unroll
        for (int af = 0; af < 2; ++af)
#pragma unroll
            for (int bf = 0; bf < 4; ++bf)
                a2[af][bf] = __builtin_amdgcn_mfma_f32_16x16x32_bf16(
                    w[af], b[bf], a2[af][bf], 0, 0, 0);
    }
    __syncthreads();   // drain t1 reads before hbf overwrites pool

#pragma unroll
    for (int af = 0; af < 2; ++af) {
        int oc0 = (nw * 2 + af) * 16 + lk * 4;
        f32x4 bias = *(const f32x4*)&b1b[oc0];
#pragma unroll
        for (int bf = 0; bf < 4; ++bf) {
            s16x4 pk;
#pragma unroll
            for (int j = 0; j < 4; ++j)
                pk[j] = f2bf(a2[af][bf][j] + bias[j]);
            *(s16x4*)&hbf[(bf * 16 + l15) * 136 + oc0] = pk;
        }
    }
    __syncthreads();

    {
        const int half = tid >> 7;
        const int c = tid & 127;
        const int slo = half * 32, shi = slo + 32;
        float sum = 0.f;
        int cur = rows[slo];
        bool first = true;
        for (int i = slo; i < shi; ++i) {
            sum += bf2f((unsigned short)hbf[i * 136 + c]);
            bool segend = (i == shi - 1) || (rows[i + 1] != cur);
            if (segend) {
                bool crossMid  = (half == 0) && (i == 31) && (rows[32] == cur);
                bool fromLower = (half == 1) && first && (rows[31] == cur);
                if (crossMid) {
                    midlo[c] = sum;
                } else if (fromLower) {
                    midhi[c] = sum;
                } else {
                    int bs = partial[cur] + boff[cur >> 8];
                    int d = deg[cur];
                    bool sh = bs >= p0, eh = bs + d <= p0 + 64;
                    if (sh && eh)      aggb[(size_t)cur * 128 + c] = f2bf(sum / (float)d);
                    else if (sh)       pend[(size_t)blockIdx.x * 128 + c] = sum;
                    else if (eh)       pstart[(size_t)blockIdx.x * 128 + c] = sum;
                }
                sum = 0.f;
                first = false;
                if (i < shi - 1) cur = rows[i + 1];
            }
        }
    }
    __syncthreads();
    if (tid < 128 && rows[31] == rows[32]) {
        int c = tid, cur = rows[32];
        float s = midlo[c] + midhi[c];
        int bs = partial[cur] + boff[cur >> 8];
        int d = deg[cur];
        bool sh = bs >= p0, eh = bs + d <= p0 + 64;
        if (sh && eh)      aggb[(size_t)cur * 128 + c] = f2bf(s / (float)d);
        else if (sh)       pend[(size_t)blockIdx.x * 128 + c] = s;
        else if (eh)       pstart[(size_t)blockIdx.x * 128 + c] = s;
    }
}

// ---------------------------------------------------------------------------
// Fixup: make aggb COMPLETE. deg==0 -> zeros; boundary -> (pend+pstart)/d.
// Interior rows already written by edge. 1.6M threads, mostly early-exit.
// ---------------------------------------------------------------------------
__global__ __launch_bounds__(256) void fixup_kernel(
    const int* __restrict__ deg, const int* __restrict__ partial,
    const int* __restrict__ boff,
    const float* __restrict__ pstart, const float* __restrict__ pend,
    short* __restrict__ aggb)
{
    int idx = blockIdx.x * 256 + threadIdx.x;   // NN*16 units
    int n = idx >> 4, ch = idx & 15;
    if (n >= NN) return;
    int d = deg[n];
    if (d == 0) {
        s16x8 z = {0, 0, 0, 0, 0, 0, 0, 0};
        *(s16x8*)&aggb[(size_t)n * 128 + ch * 8] = z;
        return;
    }
    int bs = partial[n] + boff[n >> 8];
    if ((bs & 63) + d > 64) {                   // straddles blocks k/k+1
        int k = bs >> 6;
        float inv = 1.0f / (float)d;
        const float* pe = &pend[(size_t)k * 128 + ch * 8];
        const float* ps = &pstart[(size_t)(k + 1) * 128 + ch * 8];
        s16x8 v;
#pragma unroll
        for (int j = 0; j < 8; ++j)
            v[j] = f2bf((pe[j] + ps[j]) * inv);
        *(s16x8*)&aggb[(size_t)n * 128 + ch * 8] = v;
    }
}

// ---------------------------------------------------------------------------
// Node MFMA v6: L1 A-fragments DIRECT FROM GLOBAL (aggb complete after fixup;
// ks<4 -> aggb, ks==4 -> xu for lk==0). No descriptor phase, no staging
// phase; ONE barrier (epi1 -> L2). LDS = tb only (32KB). Rows >= NN over-read
// padded aggb/xu garbage -- flows only to unsaved output columns.
// ---------------------------------------------------------------------------
__global__ __launch_bounds__(512, 4) void node_mfma_kernel(
    const short* __restrict__ aggb, const short* __restrict__ xu,
    const short* __restrict__ W2aF, const short* __restrict__ W2bF,
    const float* __restrict__ b2a, const float* __restrict__ b2b,
    float* __restrict__ out)
{
    __shared__ short tb[64 * 256];   // 32KB
    const int tid = threadIdx.x;
    const int node0 = blockIdx.x * 64;
    const int lane = tid & 63, nw = tid >> 6;
    const int l15 = lane & 15, lk = lane >> 4;

    // ---- layer 1: K=160 (5 ksteps), A-frags from global
    f32x4 acc1[4][2];
#pragma unroll
    for (int mf = 0; mf < 4; ++mf)
#pragma unroll
        for (int nf = 0; nf < 2; ++nf)
            acc1[mf][nf] = (f32x4){0.f, 0.f, 0.f, 0.f};

#pragma unroll
    for (int ks = 0; ks < 5; ++ks) {
        s16x8 a[4], w[2];
#pragma unroll
        for (int mf = 0; mf < 4; ++mf) {
            int node = node0 + mf * 16 + l15;
            if (ks < 4) {
                a[mf] = *(const s16x8*)&aggb[(size_t)node * 128 + ks * 32 + lk * 8];
            } else {
                s16x8 z = {0, 0, 0, 0, 0, 0, 0, 0};
                a[mf] = z;
                if (lk == 0)
                    a[mf] = *(const s16x8*)&xu[(size_t)node * 8];
            }
        }
#pragma unroll
        for (int nf = 0; nf < 2; ++nf)
            w[nf] = *(const s16x8*)&W2aF[((((nw * 2 + nf) * 5) + ks) * 64 + lane) * 8];
#pragma unroll
        for (int mf = 0; mf < 4; ++mf)
#pragma unroll
            for (int nf = 0; nf < 2; ++nf)
                acc1[mf][nf] = __builtin_amdgcn_mfma_f32_16x16x32_bf16(
                    w[nf], a[mf], acc1[mf][nf], 0, 0, 0);
    }

    // ---- epilogue 1: relu+bias -> tb (swizzled), 4-consec n per b64 write
#pragma unroll
    for (int nf = 0; nf < 2; ++nf) {
        int n0 = nw * 32 + nf * 16 + lk * 4;
        f32x4 bias = *(const f32x4*)&b2a[n0];
        int ch = n0 >> 3, off = n0 & 7;
#pragma unroll
        for (int mf = 0; mf < 4; ++mf) {
            int m = mf * 16 + l15;
            s16x4 pk;
#pragma unroll
            for (int j = 0; j < 4; ++j)
                pk[j] = f2bf(fmaxf(acc1[mf][nf][j] + bias[j], 0.f));
            int sw = (ch & ~7) | ((ch ^ m) & 7);
            *(s16x4*)&tb[m * 256 + sw * 8 + off] = pk;
        }
    }
    __syncthreads();

    // ---- layer 2: K=256 (8 ksteps)
    f32x4 acc2[4][4];
#pragma unroll
    for (int mf = 0; mf < 4; ++mf)
#pragma unroll
        for (int nf = 0; nf < 4; ++nf)
            acc2[mf][nf] = (f32x4){0.f, 0.f, 0.f, 0.f};

#pragma unroll
    for (int ks = 0; ks < 8; ++ks) {
        s16x8 b[4], w[4];
        int cb = ks * 4 + lk;
#pragma unroll
        for (int mf = 0; mf < 4; ++mf) {
            int r = mf * 16 + l15;
            int sw = (cb & ~7) | ((cb ^ r) & 7);
            b[mf] = *(const s16x8*)&tb[r * 256 + sw * 8];
        }
#pragma unroll
        for (int nf = 0; nf < 4; ++nf)
            w[nf] = *(const s16x8*)&W2bF[((((nw * 4 + nf) * 8) + ks) * 64 + lane) * 8];
#pragma unroll
        for (int mf = 0; mf < 4; ++mf)
#pragma unroll
            for (int nf = 0; nf < 4; ++nf)
                acc2[mf][nf] = __builtin_amdgcn_mfma_f32_16x16x32_bf16(
                    w[nf], b[mf], acc2[mf][nf], 0, 0, 0);
    }

    // ---- epilogue 2: bias + nontemporal f32x4 stores
#pragma unroll
    for (int nf = 0; nf < 4; ++nf) {
        int n0 = nw * 64 + nf * 16 + lk * 4;
        f32x4 bias = *(const f32x4*)&b2b[n0];
#pragma unroll
        for (int mf = 0; mf < 4; ++mf) {
            int node = node0 + mf * 16 + l15;
            if (node < NN) {
                f32x4 o = acc2[mf][nf] + bias;
                __builtin_nontemporal_store(o, (f32x4*)&out[(size_t)node * 512 + n0]);
            }
        }
    }
}

extern "C" void kernel_launch(void* const* d_in, const int* in_sizes, int n_in,
                              void* d_out, int out_size, void* d_ws, size_t ws_size,
                              hipStream_t stream) {
    const float* x          = (const float*)d_in[0];
    const int*   edge_index = (const int*)d_in[1];
    const float* edge_attr  = (const float*)d_in[2];
    const float* u          = (const float*)d_in[3];
    const int*   batch      = (const int*)d_in[4];
    const float* W1a        = (const float*)d_in[5];
    const float* b1a        = (const float*)d_in[6];
    const float* W1b        = (const float*)d_in[7];
    const float* b1b        = (const float*)d_in[8];
    const float* W2a        = (const float*)d_in[9];
    const float* b2a        = (const float*)d_in[10];
    const float* W2b        = (const float*)d_in[11];
    const float* b2b        = (const float*)d_in[12];
    float* out = (float*)d_out;

    // workspace layout (aggb/xu padded to NP rows for safe tile over-read)
    short* aggb   = (short*)d_ws;                        // [NP,128] bf16
    short* xu     = aggb + (size_t)NP * 128;             // [NP,8] bf16
    short* W2aF   = xu + (size_t)NP * 8;                 // [16*5*512] bf16
    short* W2bF   = W2aF + 16 * 5 * 512;                 // [32*8*512] bf16
    short* W1aT   = W2bF + 32 * 8 * 512;                 // [64,32]   bf16
    short* W1bT   = W1aT + 64 * 32;                      // [128,64]  bf16
    int*   deg    = (int*)(W1bT + 128 * 64);             // [NP]
    int*   cnt2   = deg + NP;                            // [NP] (memset with deg)
    int*   partial= cnt2 + NP;                           // [NP]
    int*   bsum   = partial + NP;                        // [512]
    int*   boff   = bsum + 512;                          // [512]
    int*   rowp   = boff + 512;                          // [NE]
    float* pstart = (float*)(rowp + NE);                 // [NBE,128]
    float* pend   = pstart + (size_t)NBE * 128;          // [NBE,128]
    short* in_csr = (short*)(pend + (size_t)NBE * 128);  // [NE,8] bf16

    hipMemsetAsync(deg, 0, 2 * NP * sizeof(int), stream);

    hist_prep_kernel<<<(NE + 255) / 256, 256, 0, stream>>>(
        edge_index, deg, x, u, batch, W2a, W2b, W1a, W1b,
        W2aF, W2bF, W1aT, W1bT, xu);
    scan1_kernel<<<NB, 256, 0, stream>>>(deg, partial, bsum);
    scan2_kernel<<<1, 512, 0, stream>>>(bsum, boff);
    fill_kernel <<<(NE + 255) / 256, 256, 0, stream>>>(edge_index, x, edge_attr,
                                                       partial, boff, cnt2,
                                                       rowp, in_csr);

    edge_fused_kernel<<<NBE, 256, 0, stream>>>(
        in_csr, rowp, W1aT, W1bT, b1a, b1b,
        partial, boff, deg, aggb, pstart, pend);

    fixup_kernel<<<(NN * 16 + 255) / 256, 256, 0, stream>>>(
        deg, partial, boff, pstart, pend, aggb);

    node_mfma_kernel<<<(NN + 63) / 64, 512, 0, stream>>>(
        aggb, xu, W2aF, W2bF, b2a, b2b, out);
}

// Round 23
// 211.064 us; speedup vs baseline: 1.0912x; 1.0912x over previous
//
#include <hip/hip_runtime.h>

#define NN 100000
#define NE 600000
#define NP 100096   // 391*256, padded node count
#define NB 391
#define NBE 9375    // NE/64 edge blocks

typedef float v4    __attribute__((ext_vector_type(4)));
typedef float f32x4 __attribute__((ext_vector_type(4)));
typedef short s16x4 __attribute__((ext_vector_type(4)));
typedef short s16x8 __attribute__((ext_vector_type(8)));

__device__ __forceinline__ short f2bf(float f) {
    unsigned u = __float_as_uint(f);
    u = (u + 0x7fffu + ((u >> 16) & 1u)) >> 16;
    return (short)u;
}
__device__ __forceinline__ float bf2f(unsigned short v) {
    return __uint_as_float(((unsigned)v) << 16);
}

// ---------------------------------------------------------------------------
// hist + weight-prep fused.
// ---------------------------------------------------------------------------
__global__ __launch_bounds__(256) void hist_prep_kernel(
    const int* __restrict__ ei, int* __restrict__ deg,
    const float* __restrict__ W2a, const float* __restrict__ W2b,
    const float* __restrict__ W1a, const float* __restrict__ W1b,
    short* __restrict__ W2aF, short* __restrict__ W2bF,
    short* __restrict__ W1aT, short* __restrict__ W1bT)
{
    int idx = blockIdx.x * 256 + threadIdx.x;
    if (idx < NE) atomicAdd(&deg[ei[idx]], 1);

    if (idx < 16 * 5 * 512) {                     // W2aF: 40960
        int j = idx & 7;
        int lane = (idx >> 3) & 63;
        int t2 = idx >> 9;
        int ks = t2 % 5, nb = t2 / 5;
        int n = nb * 16 + (lane & 15);
        int k = ks * 32 + (lane >> 4) * 8 + j;    // < 160
        float v = 0.f;
        if (k < 128)       v = W2a[(2 + k) * 256 + n];
        else if (k == 128) v = W2a[0 * 256 + n];
        else if (k == 129) v = W2a[1 * 256 + n];
        else if (k == 130) v = W2a[130 * 256 + n];
        else if (k == 131) v = W2a[131 * 256 + n];
        W2aF[idx] = f2bf(v);
    }
    if (idx < 32 * 8 * 512) {                     // W2bF: 131072
        int j = idx & 7;
        int lane = (idx >> 3) & 63;
        int t2 = idx >> 9;
        int ks = t2 & 7, nb = t2 >> 3;
        int n = nb * 16 + (lane & 15);
        int k = ks * 32 + (lane >> 4) * 8 + j;    // < 256
        W2bF[idx] = f2bf(W2b[k * 512 + n]);
    }
    if (idx < 64 * 32) {
        int n = idx >> 5, k = idx & 31;
        W1aT[idx] = (k < 4) ? f2bf(W1a[k * 64 + n]) : (short)0;
    }
    if (idx < 128 * 64) {
        int n = idx >> 6, k = idx & 63;
        W1bT[idx] = f2bf(W1b[k * 128 + n]);
    }
}

__global__ __launch_bounds__(256) void scan1_kernel(const int* __restrict__ deg,
                                                    int* __restrict__ partial,
                                                    int* __restrict__ bsum) {
    __shared__ int tmp[256];
    int t = threadIdx.x;
    int i = blockIdx.x * 256 + t;
    int v = deg[i];
    tmp[t] = v;
    __syncthreads();
    for (int off = 1; off < 256; off <<= 1) {
        int add = (t >= off) ? tmp[t - off] : 0;
        __syncthreads();
        tmp[t] += add;
        __syncthreads();
    }
    partial[i] = tmp[t] - v;
    if (t == 255) bsum[blockIdx.x] = tmp[255];
}

__global__ __launch_bounds__(512) void scan2_kernel(const int* __restrict__ bsum,
                                                    int* __restrict__ boff) {
    __shared__ int tmp[512];
    int t = threadIdx.x;
    int v = (t < NB) ? bsum[t] : 0;
    tmp[t] = v;
    __syncthreads();
    for (int off = 1; off < 512; off <<= 1) {
        int add = (t >= off) ? tmp[t - off] : 0;
        __syncthreads();
        tmp[t] += add;
        __syncthreads();
    }
    boff[t] = tmp[t] - v;
}

__global__ __launch_bounds__(256) void fill_kernel(const int* __restrict__ ei,
                                                   const float* __restrict__ x,
                                                   const float* __restrict__ ea,
                                                   const int* __restrict__ partial,
                                                   const int* __restrict__ boff,
                                                   int* __restrict__ cnt2,
                                                   int* __restrict__ rowp,
                                                   short* __restrict__ in_csr) {
    int e = blockIdx.x * 256 + threadIdx.x;
    if (e < NE) {
        int r = ei[e];
        int c = ei[NE + e];
        int p = partial[r] + boff[r >> 8] + atomicAdd(&cnt2[r], 1);
        rowp[p] = r;
        s16x8 v = {0, 0, 0, 0, 0, 0, 0, 0};
        v[0] = f2bf(x[2 * c]);  v[1] = f2bf(x[2 * c + 1]);
        v[2] = f2bf(ea[2 * e]); v[3] = f2bf(ea[2 * e + 1]);
        *(s16x8*)&in_csr[(size_t)p * 8] = v;
    }
}

// ---------------------------------------------------------------------------
// Edge fused v4: NO input LDS staging — the L1 B-fragment is
//   lk==0 ? 16B direct load from in_csr[row*8] : zero   (k>=8 cols are pad).
// LDS pool: t1[64*72] then hbf[64*136] (union). __launch_bounds__(256,8).
// ---------------------------------------------------------------------------
__global__ __launch_bounds__(256, 8) void edge_fused_kernel(
    const short* __restrict__ in_csr, const int* __restrict__ rowp,
    const short* __restrict__ W1aT, const short* __restrict__ W1bT,
    const float* __restrict__ b1a, const float* __restrict__ b1b,
    const int* __restrict__ partial, const int* __restrict__ boff,
    const int* __restrict__ deg,
    short* __restrict__ aggb, float* __restrict__ pstart,
    float* __restrict__ pend)
{
    __shared__ short pool[64 * 136];  // union: t1[64*72] then hbf[64*136]
    __shared__ int   rows[64];
    __shared__ float midlo[128], midhi[128];
    short* t1  = pool;                // [edge][72]
    short* hbf = pool;                // [edge][136] after L2 reads drain
    const int tid = threadIdx.x;
    const int p0 = blockIdx.x * 64;

    if (tid < 64) rows[tid] = rowp[p0 + tid];   // covered by epilogue1 barrier

    const int lane = tid & 63, nw = tid >> 6;
    const int l15 = lane & 15, lk = lane >> 4;

    // ---- L1 swapped: A=W1a(t1col,k) B=in(edge,k) direct from global
    f32x4 a1[4];
#pragma unroll
    for (int bf = 0; bf < 4; ++bf) a1[bf] = (f32x4){0.f, 0.f, 0.f, 0.f};
    {
        s16x8 wA = *(const s16x8*)&W1aT[(nw * 16 + l15) * 32 + lk * 8];
        s16x8 zz = {0, 0, 0, 0, 0, 0, 0, 0};
#pragma unroll
        for (int bf = 0; bf < 4; ++bf) {
            s16x8 bI = zz;
            if (lk == 0)
                bI = *(const s16x8*)&in_csr[(size_t)(p0 + bf * 16 + l15) * 8];
            a1[bf] = __builtin_amdgcn_mfma_f32_16x16x32_bf16(wA, bI, a1[bf], 0, 0, 0);
        }
    }
    // ---- epilogue1 -> t1
    {
        f32x4 bias = *(const f32x4*)&b1a[nw * 16 + lk * 4];
#pragma unroll
        for (int bf = 0; bf < 4; ++bf) {
            s16x4 pk;
#pragma unroll
            for (int j = 0; j < 4; ++j)
                pk[j] = f2bf(fmaxf(a1[bf][j] + bias[j], 0.f));
            *(s16x4*)&t1[(bf * 16 + l15) * 72 + nw * 16 + lk * 4] = pk;
        }
    }
    __syncthreads();

    // ---- L2 swapped: wave nw -> outcols nw*32..+32
    f32x4 a2[2][4];
#pragma unroll
    for (int af = 0; af < 2; ++af)
#pragma unroll
        for (int bf = 0; bf < 4; ++bf) a2[af][bf] = (f32x4){0.f, 0.f, 0.f, 0.f};

#pragma unroll
    for (int ks = 0; ks < 2; ++ks) {
        s16x8 w[2], b[4];
#pragma unroll
        for (int af = 0; af < 2; ++af)
            w[af] = *(const s16x8*)&W1bT[((nw * 2 + af) * 16 + l15) * 64 + ks * 32 + lk * 8];
#pragma unroll
        for (int bf = 0; bf < 4; ++bf)
            b[bf] = *(const s16x8*)&t1[(bf * 16 + l15) * 72 + ks * 32 + lk * 8];
#pragma unroll
        for (int af = 0; af < 2; ++af)
#pragma unroll
            for (int bf = 0; bf < 4; ++bf)
                a2[af][bf] = __builtin_amdgcn_mfma_f32_16x16x32_bf16(
                    w[af], b[bf], a2[af][bf], 0, 0, 0);
    }
    __syncthreads();   // drain t1 reads before hbf overwrites pool

    // ---- epilogue2 -> hbf (pool reuse)
#pragma unroll
    for (int af = 0; af < 2; ++af) {
        int oc0 = (nw * 2 + af) * 16 + lk * 4;
        f32x4 bias = *(const f32x4*)&b1b[oc0];
#pragma unroll
        for (int bf = 0; bf < 4; ++bf) {
            s16x4 pk;
#pragma unroll
            for (int j = 0; j < 4; ++j)
                pk[j] = f2bf(a2[af][bf][j] + bias[j]);
            *(s16x4*)&hbf[(bf * 16 + l15) * 136 + oc0] = pk;
        }
    }
    __syncthreads();

    // ---- segmented reduce: two 32-slot halves, all 256 threads
    {
        const int half = tid >> 7;
        const int c = tid & 127;
        const int slo = half * 32, shi = slo + 32;
        float sum = 0.f;
        int cur = rows[slo];
        bool first = true;
        for (int i = slo; i < shi; ++i) {
            sum += bf2f((unsigned short)hbf[i * 136 + c]);
            bool segend = (i == shi - 1) || (rows[i + 1] != cur);
            if (segend) {
                bool crossMid  = (half == 0) && (i == 31) && (rows[32] == cur);
                bool fromLower = (half == 1) && first && (rows[31] == cur);
                if (crossMid) {
                    midlo[c] = sum;
                } else if (fromLower) {
                    midhi[c] = sum;
                } else {
                    int bs = partial[cur] + boff[cur >> 8];
                    int d = deg[cur];
                    bool sh = bs >= p0, eh = bs + d <= p0 + 64;
                    if (sh && eh)      aggb[(size_t)cur * 128 + c] = f2bf(sum / (float)d);
                    else if (sh)       pend[(size_t)blockIdx.x * 128 + c] = sum;
                    else if (eh)       pstart[(size_t)blockIdx.x * 128 + c] = sum;
                }
                sum = 0.f;
                first = false;
                if (i < shi - 1) cur = rows[i + 1];
            }
        }
    }
    __syncthreads();
    // ---- mid-merge: the (single) node crossing slot 31/32
    if (tid < 128 && rows[31] == rows[32]) {
        int c = tid, cur = rows[32];
        float s = midlo[c] + midhi[c];
        int bs = partial[cur] + boff[cur >> 8];
        int d = deg[cur];
        bool sh = bs >= p0, eh = bs + d <= p0 + 64;
        if (sh && eh)      aggb[(size_t)cur * 128 + c] = f2bf(s / (float)d);
        else if (sh)       pend[(size_t)blockIdx.x * 128 + c] = s;
        else if (eh)       pstart[(size_t)blockIdx.x * 128 + c] = s;
    }
}

// ---------------------------------------------------------------------------
// Node MFMA v5 (proven 211.1 µs): LDS staging (zero/interior/boundary modes),
// swapped operands, frag-major weights, LDS union, nontemporal out stores.
// ---------------------------------------------------------------------------
__global__ __launch_bounds__(512, 4) void node_mfma_kernel(
    const float* __restrict__ x, const float* __restrict__ u,
    const int* __restrict__ batch,
    const short* __restrict__ aggb,
    const int* __restrict__ deg, const int* __restrict__ partial,
    const int* __restrict__ boff,
    const float* __restrict__ pstart, const float* __restrict__ pend,
    const short* __restrict__ W2aF, const short* __restrict__ W2bF,
    const float* __restrict__ b2a, const float* __restrict__ b2b,
    float* __restrict__ out)
{
    __shared__ short lds[64 * 256];   // union: zb[64][192] then tb[64][256]
    __shared__ int   rmode[64];
    __shared__ float rinv[64];
    __shared__ int   rk[64];
    const int tid = threadIdx.x;
    const int node0 = blockIdx.x * 64;

    if (tid < 64) {
        int node = node0 + tid;
        int mode = 0, k = 0;
        float inv = 0.f;
        if (node < NN) {
            int d = deg[node];
            if (d > 0) {
                int bs = partial[node] + boff[node >> 8];
                k = bs >> 6;
                mode = ((bs & 63) + d > 64) ? 2 : 1;
                inv = 1.0f / (float)d;
            }
        }
        rmode[tid] = mode; rinv[tid] = inv; rk[tid] = k;
    }
    __syncthreads();

#pragma unroll
    for (int it = 0; it < 2; ++it) {
        int idx = it * 512 + tid;         // 1024 = 64 rows * 16 chunks
        int r = idx >> 4, ch = idx & 15;
        int node = node0 + r;
        int mode = rmode[r];
        s16x8 v = {0, 0, 0, 0, 0, 0, 0, 0};
        if (mode == 1) {
            v = *(const s16x8*)&aggb[(size_t)node * 128 + ch * 8];
        } else if (mode == 2) {
            float inv = rinv[r];
            int k = rk[r];
            const float* pe = &pend[(size_t)k * 128 + ch * 8];
            const float* ps = &pstart[(size_t)(k + 1) * 128 + ch * 8];
#pragma unroll
            for (int j = 0; j < 8; ++j)
                v[j] = f2bf((pe[j] + ps[j]) * inv);
        }
        int sw = (ch & ~7) | ((ch ^ r) & 7);
        *(s16x8*)&lds[r * 192 + sw * 8] = v;
    }
    if (tid < 64) {
        int r = tid, node = node0 + r;
        s16x8 p = {0, 0, 0, 0, 0, 0, 0, 0};
        if (node < NN) {
            p[0] = f2bf(x[node * 2]); p[1] = f2bf(x[node * 2 + 1]);
            int b = batch[node];
            p[2] = f2bf(u[b * 2]); p[3] = f2bf(u[b * 2 + 1]);
        }
        int sw = 16 | (r & 7);
        *(s16x8*)&lds[r * 192 + sw * 8] = p;
    } else if (tid < 256) {
        int t2 = tid - 64;
        int r = t2 & 63;
        int ch = 17 + (t2 >> 6);
        int sw = (ch & ~7) | ((ch ^ r) & 7);
        s16x8 zz = {0, 0, 0, 0, 0, 0, 0, 0};
        *(s16x8*)&lds[r * 192 + sw * 8] = zz;
    }
    __syncthreads();

    const int lane = tid & 63, nw = tid >> 6;
    const int l15 = lane & 15, lk = lane >> 4;

    f32x4 acc1[4][2];
#pragma unroll
    for (int mf = 0; mf < 4; ++mf)
#pragma unroll
        for (int nf = 0; nf < 2; ++nf)
            acc1[mf][nf] = (f32x4){0.f, 0.f, 0.f, 0.f};

#pragma unroll
    for (int ks = 0; ks < 5; ++ks) {
        s16x8 a[4], w[2];
        int cb = ks * 4 + lk;
#pragma unroll
        for (int mf = 0; mf < 4; ++mf) {
            int r = mf * 16 + l15;
            int sw = (cb & ~7) | ((cb ^ r) & 7);
            a[mf] = *(const s16x8*)&lds[r * 192 + sw * 8];
        }
#pragma unroll
        for (int nf = 0; nf < 2; ++nf)
            w[nf] = *(const s16x8*)&W2aF[((((nw * 2 + nf) * 5) + ks) * 64 + lane) * 8];
#pragma unroll
        for (int mf = 0; mf < 4; ++mf)
#pragma unroll
            for (int nf = 0; nf < 2; ++nf)
                acc1[mf][nf] = __builtin_amdgcn_mfma_f32_16x16x32_bf16(
                    w[nf], a[mf], acc1[mf][nf], 0, 0, 0);
    }
    __syncthreads();

#pragma unroll
    for (int nf = 0; nf < 2; ++nf) {
        int n0 = nw * 32 + nf * 16 + lk * 4;
        f32x4 bias = *(const f32x4*)&b2a[n0];
        int ch = n0 >> 3, off = n0 & 7;
#pragma unroll
        for (int mf = 0; mf < 4; ++mf) {
            int m = mf * 16 + l15;
            s16x4 pk;
#pragma unroll
            for (int j = 0; j < 4; ++j)
                pk[j] = f2bf(fmaxf(acc1[mf][nf][j] + bias[j], 0.f));
            int sw = (ch & ~7) | ((ch ^ m) & 7);
            *(s16x4*)&lds[m * 256 + sw * 8 + off] = pk;
        }
    }
    __syncthreads();

    f32x4 acc2[4][4];
#pragma unroll
    for (int mf = 0; mf < 4; ++mf)
#pragma unroll
        for (int nf = 0; nf < 4; ++nf)
            acc2[mf][nf] = (f32x4){0.f, 0.f, 0.f, 0.f};

#pragma unroll
    for (int ks = 0; ks < 8; ++ks) {
        s16x8 b[4], w[4];
        int cb = ks * 4 + lk;
#pragma unroll
        for (int mf = 0; mf < 4; ++mf) {
            int r = mf * 16 + l15;
            int sw = (cb & ~7) | ((cb ^ r) & 7);
            b[mf] = *(const s16x8*)&lds[r * 256 + sw * 8];
        }
#pragma unroll
        for (int nf = 0; nf < 4; ++nf)
            w[nf] = *(const s16x8*)&W2bF[((((nw * 4 + nf) * 8) + ks) * 64 + lane) * 8];
#pragma unroll
        for (int mf = 0; mf < 4; ++mf)
#pragma unroll
            for (int nf = 0; nf < 4; ++nf)
                acc2[mf][nf] = __builtin_amdgcn_mfma_f32_16x16x32_bf16(
                    w[nf], b[mf], acc2[mf][nf], 0, 0, 0);
    }

#pragma unroll
    for (int nf = 0; nf < 4; ++nf) {
        int n0 = nw * 64 + nf * 16 + lk * 4;
        f32x4 bias = *(const f32x4*)&b2b[n0];
#pragma unroll
        for (int mf = 0; mf < 4; ++mf) {
            int node = node0 + mf * 16 + l15;
            if (node < NN) {
                f32x4 o = acc2[mf][nf] + bias;
                __builtin_nontemporal_store(o, (f32x4*)&out[(size_t)node * 512 + n0]);
            }
        }
    }
}

extern "C" void kernel_launch(void* const* d_in, const int* in_sizes, int n_in,
                              void* d_out, int out_size, void* d_ws, size_t ws_size,
                              hipStream_t stream) {
    const float* x          = (const float*)d_in[0];
    const int*   edge_index = (const int*)d_in[1];
    const float* edge_attr  = (const float*)d_in[2];
    const float* u          = (const float*)d_in[3];
    const int*   batch      = (const int*)d_in[4];
    const float* W1a        = (const float*)d_in[5];
    const float* b1a        = (const float*)d_in[6];
    const float* W1b        = (const float*)d_in[7];
    const float* b1b        = (const float*)d_in[8];
    const float* W2a        = (const float*)d_in[9];
    const float* b2a        = (const float*)d_in[10];
    const float* W2b        = (const float*)d_in[11];
    const float* b2b        = (const float*)d_in[12];
    float* out = (float*)d_out;

    // workspace layout
    short* aggb   = (short*)d_ws;                        // [NN,128] bf16
    short* W2aF   = aggb + (size_t)NN * 128;             // [16*5*512] bf16
    short* W2bF   = W2aF + 16 * 5 * 512;                 // [32*8*512] bf16
    short* W1aT   = W2bF + 32 * 8 * 512;                 // [64,32]   bf16
    short* W1bT   = W1aT + 64 * 32;                      // [128,64]  bf16
    int*   deg    = (int*)(W1bT + 128 * 64);             // [NP]
    int*   cnt2   = deg + NP;                            // [NP] (memset with deg)
    int*   partial= cnt2 + NP;                           // [NP]
    int*   bsum   = partial + NP;                        // [512]
    int*   boff   = bsum + 512;                          // [512]
    int*   rowp   = boff + 512;                          // [NE]
    float* pstart = (float*)(rowp + NE);                 // [NBE,128]
    float* pend   = pstart + (size_t)NBE * 128;          // [NBE,128]
    short* in_csr = (short*)(pend + (size_t)NBE * 128);  // [NE,8] bf16

    hipMemsetAsync(deg, 0, 2 * NP * sizeof(int), stream);

    hist_prep_kernel<<<(NE + 255) / 256, 256, 0, stream>>>(
        edge_index, deg, W2a, W2b, W1a, W1b, W2aF, W2bF, W1aT, W1bT);
    scan1_kernel<<<NB, 256, 0, stream>>>(deg, partial, bsum);
    scan2_kernel<<<1, 512, 0, stream>>>(bsum, boff);
    fill_kernel <<<(NE + 255) / 256, 256, 0, stream>>>(edge_index, x, edge_attr,
                                                       partial, boff, cnt2,
                                                       rowp, in_csr);

    edge_fused_kernel<<<NBE, 256, 0, stream>>>(
        in_csr, rowp, W1aT, W1bT, b1a, b1b,
        partial, boff, deg, aggb, pstart, pend);

    node_mfma_kernel<<<(NN + 63) / 64, 512, 0, stream>>>(
        x, u, batch, aggb, deg, partial, boff, pstart, pend,
        W2aF, W2bF, b2a, b2b, out);
}